// Round 7
// baseline (438.777 us; speedup 1.0000x reference)
//
#include <hip/hip_runtime.h>

typedef unsigned short u16;
typedef __attribute__((ext_vector_type(8))) __bf16 bf16x8;
typedef __attribute__((ext_vector_type(8))) unsigned short u16x8;
typedef __attribute__((ext_vector_type(4))) float f32x4;
typedef __attribute__((ext_vector_type(16))) float f32x16;

#define BK 32
#define TILE_ELEMS (128 * BK)

__device__ __forceinline__ u16 f32_to_bf16(float f) {
  unsigned int u = __builtin_bit_cast(unsigned int, f);
  u += 0x7fffu + ((u >> 16) & 1u);
  return (u16)(u >> 16);
}

// async global->LDS DMA, 16B/lane; LDS dst = wave-uniform base + lane*16
__device__ __forceinline__ void gload_lds16(const u16* g, u16* l) {
  __builtin_amdgcn_global_load_lds(
      (const __attribute__((address_space(1))) void*)g,
      (__attribute__((address_space(3))) void*)l, 16, 0, 0);
}

// ---------------- fp32 -> bf16 conversion ----------------
__global__ __launch_bounds__(256) void cvt_bf16(const float* __restrict__ in,
                                                u16* __restrict__ out, int n) {
  int i = (blockIdx.x * 256 + threadIdx.x) * 4;
  if (i >= n) return;
  float4 v = *(const float4*)(in + i);
  ushort4 o;
  o.x = f32_to_bf16(v.x);
  o.y = f32_to_bf16(v.y);
  o.z = f32_to_bf16(v.z);
  o.w = f32_to_bf16(v.w);
  *(ushort4*)(out + i) = o;
}

// ------------- GEMM core: C(128x128) = A_tile(128xK) * B_tile(128xK)^T ------
// global_load_lds (width 16) + single-barrier double buffer:
//   barrier (drains DMA of tile k; __syncthreads implies vmcnt(0))
//   -> issue DMA tile k+1 into buf p^1 (flies during compute)
//   -> MFMA from buf p.
// Race: buf p^1's prior readers (tile k-1, iter k-1) passed the barrier at
// iter k before the DMA issues. Lane map: wave-uniform LDS base As+w*64*8,
// lane writes +lane*16B -> element (w*64+lane)*8 = tid*8, matching the
// (row=tid>>2, chunk=tid&3) global address. [m97 pattern]
__device__ __forceinline__ void gemm_core(const u16* __restrict__ A_tile,
                                          const u16* __restrict__ B_tile, int K,
                                          u16* As, u16* Bs, f32x4 acc[4][4]) {
  const int tid = threadIdx.x;
  const int w = tid >> 6, lane = tid & 63;
  const int wm = (w >> 1) << 6, wn = (w & 1) << 6;
  const int quad = lane >> 4, l15 = lane & 15;

  const u16* Ap = A_tile + (tid >> 2) * K + (tid & 3) * 8;
  const u16* Bp = B_tile + (tid >> 2) * K + (tid & 3) * 8;
  const int ldsOff0 = (w * 64) * 8;           // wave-uniform
  const int ldsOff1 = (256 + w * 64) * 8;

  // prologue: DMA tile 0 into buf 0
  gload_lds16(Ap, As + ldsOff0);
  gload_lds16(Ap + 64 * K, As + ldsOff1);
  gload_lds16(Bp, Bs + ldsOff0);
  gload_lds16(Bp + 64 * K, Bs + ldsOff1);

  int p = 0;
  for (int k0 = 0; k0 < K; k0 += BK) {
    __syncthreads();  // tile k DMA complete (vmcnt 0) + all readers of k-1 done
    if (k0 + BK < K) {
      const int kn = k0 + BK;
      u16* Asw = As + (p ^ 1) * TILE_ELEMS;
      u16* Bsw = Bs + (p ^ 1) * TILE_ELEMS;
      gload_lds16(Ap + kn, Asw + ldsOff0);
      gload_lds16(Ap + 64 * K + kn, Asw + ldsOff1);
      gload_lds16(Bp + kn, Bsw + ldsOff0);
      gload_lds16(Bp + 64 * K + kn, Bsw + ldsOff1);
    }
    const u16* Asr = As + p * TILE_ELEMS;
    const u16* Bsr = Bs + p * TILE_ELEMS;
    bf16x8 af[4], bf[4];
#pragma unroll
    for (int i = 0; i < 4; i++)
      af[i] = *(const bf16x8*)(Asr + (wm + i * 16 + l15) * BK + quad * 8);
#pragma unroll
    for (int j = 0; j < 4; j++)
      bf[j] = *(const bf16x8*)(Bsr + (wn + j * 16 + l15) * BK + quad * 8);
#pragma unroll
    for (int i = 0; i < 4; i++)
#pragma unroll
      for (int j = 0; j < 4; j++)
        acc[i][j] =
            __builtin_amdgcn_mfma_f32_16x16x32_bf16(af[i], bf[j], acc[i][j], 0, 0, 0);
    p ^= 1;
  }
}

// ---------------- fused q-proj + latent-proj ----------------
__global__ __launch_bounds__(256) void gemm_qlat(const u16* __restrict__ X,
                                                 const u16* __restrict__ QW,
                                                 const u16* __restrict__ KVDW,
                                                 const float* __restrict__ q_b,
                                                 const float* __restrict__ kvd_b,
                                                 u16* __restrict__ Qb,
                                                 u16* __restrict__ Lat) {
  __shared__ __align__(16) u16 As[2 * TILE_ELEMS];
  __shared__ __align__(16) u16 Bs[2 * TILE_ELEMS];
  const int bn = blockIdx.x, bm = blockIdx.y;
  const bool isq = bn < 16;
  const u16* B_tile = isq ? QW + (size_t)bn * 128 * 2048
                          : KVDW + (size_t)(bn - 16) * 128 * 2048;
  f32x4 acc[4][4];
  const f32x4 z = {0.f, 0.f, 0.f, 0.f};
#pragma unroll
  for (int i = 0; i < 4; i++)
#pragma unroll
    for (int j = 0; j < 4; j++) acc[i][j] = z;
  gemm_core(X + (size_t)bm * 128 * 2048, B_tile, 2048, As, Bs, acc);

  const float* bias = isq ? q_b : kvd_b;
  u16* C = isq ? Qb : Lat;
  const int N = isq ? 2048 : 512;
  const int colbase = (isq ? bn : bn - 16) * 128;

  const int tid = threadIdx.x;
  const int w = tid >> 6, lane = tid & 63;
  const int wm = (w >> 1) << 6, wn = (w & 1) << 6;
  const int quad = lane >> 4, l15 = lane & 15;
  const int row0 = bm * 128 + wm + quad * 4;
  const int col0 = colbase + wn + l15;
#pragma unroll
  for (int i = 0; i < 4; i++)
#pragma unroll
    for (int j = 0; j < 4; j++) {
      int col = col0 + j * 16;
      float bv = bias[col];
#pragma unroll
      for (int r = 0; r < 4; r++) {
        int row = row0 + i * 16 + r;
        C[(size_t)row * N + col] = f32_to_bf16(acc[i][j][r] + bv);
      }
    }
}

// ---------------- GEMM with fp32 output (final projection) ----------------
__global__ __launch_bounds__(256) void gemm_f32out(const u16* __restrict__ A,
                                                   const u16* __restrict__ B,
                                                   const float* __restrict__ bias,
                                                   float* __restrict__ C, int K, int N) {
  __shared__ __align__(16) u16 As[2 * TILE_ELEMS];
  __shared__ __align__(16) u16 Bs[2 * TILE_ELEMS];
  f32x4 acc[4][4];
  const f32x4 z = {0.f, 0.f, 0.f, 0.f};
#pragma unroll
  for (int i = 0; i < 4; i++)
#pragma unroll
    for (int j = 0; j < 4; j++) acc[i][j] = z;
  gemm_core(A + (size_t)blockIdx.y * 128 * K, B + (size_t)blockIdx.x * 128 * K, K,
            As, Bs, acc);

  const int tid = threadIdx.x;
  const int w = tid >> 6, lane = tid & 63;
  const int wm = (w >> 1) << 6, wn = (w & 1) << 6;
  const int quad = lane >> 4, l15 = lane & 15;
  const int row0 = blockIdx.y * 128 + wm + quad * 4;
  const int col0 = blockIdx.x * 128 + wn + l15;
#pragma unroll
  for (int i = 0; i < 4; i++)
#pragma unroll
    for (int j = 0; j < 4; j++) {
      int col = col0 + j * 16;
      float bv = bias[col];
#pragma unroll
      for (int r = 0; r < 4; r++) {
        int row = row0 + i * 16 + r;
        C[(size_t)row * N + col] = acc[i][j][r] + bv;
      }
    }
}

// ------------- GEMM3: kv-up with scatter epilogue: K->(b,h,s,d), V->(b,h,d,s) -
__global__ __launch_bounds__(256) void gemm_kv(const u16* __restrict__ A,
                                               const u16* __restrict__ B,
                                               const float* __restrict__ bias,
                                               u16* __restrict__ Khat,
                                               u16* __restrict__ Vt, int K) {
  __shared__ __align__(16) u16 As[2 * TILE_ELEMS];
  __shared__ __align__(16) u16 Bs[2 * TILE_ELEMS];
  f32x4 acc[4][4];
  const f32x4 z = {0.f, 0.f, 0.f, 0.f};
#pragma unroll
  for (int i = 0; i < 4; i++)
#pragma unroll
    for (int j = 0; j < 4; j++) acc[i][j] = z;
  gemm_core(A + (size_t)blockIdx.y * 128 * K, B + (size_t)blockIdx.x * 128 * K, K,
            As, Bs, acc);

  const int tid = threadIdx.x;
  const int w = tid >> 6, lane = tid & 63;
  const int wm = (w >> 1) << 6, wn = (w & 1) << 6;
  const int quad = lane >> 4, l15 = lane & 15;
  const int row0 = blockIdx.y * 128 + wm + quad * 4;
  const int col0 = blockIdx.x * 128 + wn + l15;
#pragma unroll
  for (int i = 0; i < 4; i++)
#pragma unroll
    for (int j = 0; j < 4; j++) {
      int n = col0 + j * 16;
      float bv = bias[n];
#pragma unroll
      for (int r = 0; r < 4; r++) {
        int row = row0 + i * 16 + r;   // row = b*2048 + s
        int bb = row >> 11, s = row & 2047;
        u16 val = f32_to_bf16(acc[i][j][r] + bv);
        if (n < 2048) {
          int h = n >> 7, d = n & 127;
          Khat[((size_t)(bb * 16 + h) * 2048 + s) * 128 + d] = val;
        } else {
          int h = (n - 2048) >> 7, d = n & 127;
          Vt[((size_t)(bb * 16 + h) * 128 + d) * 2048 + s] = val;
        }
      }
    }
}

// ---------------- attention: dbuf single-barrier, 32-key tiles --------------
__global__ __launch_bounds__(256) void attn_kernel(const u16* __restrict__ Q,
                                                   const u16* __restrict__ Khat,
                                                   const u16* __restrict__ Vt,
                                                   u16* __restrict__ O) {
  __shared__ __align__(16) u16 Ks[2][32 * 136];   // keys x dims (stride 136)
  __shared__ __align__(16) u16 Vs[2][128 * 40];   // dims x keys (stride 40)
  __shared__ __align__(16) u16 Ps[4 * 32 * 40];   // per-wave P (32 rows x 32 keys)

  const int tid = threadIdx.x;
  const int w = tid >> 6, lane = tid & 63;
  const int l31 = lane & 31, half = lane >> 5;
  const int qt = blockIdx.x & 15;
  const int h = (blockIdx.x >> 4) & 15;
  const int b = blockIdx.x >> 8;
  const int bh = b * 16 + h;
  const float SC = 0.08838834764831845f * 1.4426950408889634f;  // 1/sqrt(128)*log2(e)

  bf16x8 qf[8];
  {
    const u16* qrow = Q + (size_t)(b * 2048 + qt * 128 + w * 32 + l31) * 2048 +
                      h * 128 + half * 8;
#pragma unroll
    for (int kc = 0; kc < 8; kc++) qf[kc] = *(const bf16x8*)(qrow + kc * 16);
  }

  f32x16 oacc[4];
#pragma unroll
  for (int nt = 0; nt < 4; nt++)
#pragma unroll
    for (int r = 0; r < 16; r++) oacc[nt][r] = 0.f;
  float lsum[16];
#pragma unroll
  for (int r = 0; r < 16; r++) lsum[r] = 0.f;

  const u16* Kg = Khat + (size_t)bh * 2048 * 128;
  const u16* Vg = Vt + (size_t)bh * 128 * 2048;
  u16* Pw = Ps + w * 32 * 40;

  const int kkr = tid >> 4, kc0 = tid & 15;
  const int vd = tid >> 2, vc0 = tid & 3;

  u16x8 kv[2], vv[2];
#pragma unroll
  for (int it = 0; it < 2; it++) {
    kv[it] = *(const u16x8*)(Kg + (size_t)(kkr + it * 16) * 128 + kc0 * 8);
    vv[it] = *(const u16x8*)(Vg + (size_t)(vd + it * 64) * 2048 + vc0 * 8);
  }
#pragma unroll
  for (int it = 0; it < 2; it++) {
    *(u16x8*)(Ks[0] + (kkr + it * 16) * 136 + kc0 * 8) = kv[it];
    *(u16x8*)(Vs[0] + (vd + it * 64) * 40 + vc0 * 8) = vv[it];
  }

  int p = 0;
  for (int key0 = 0; key0 < 2048; key0 += 32) {
    const int kn = (key0 + 32 < 2048) ? (key0 + 32) : 0;
#pragma unroll
    for (int it = 0; it < 2; it++) {
      kv[it] = *(const u16x8*)(Kg + (size_t)(kn + kkr + it * 16) * 128 + kc0 * 8);
      vv[it] = *(const u16x8*)(Vg + (size_t)(vd + it * 64) * 2048 + kn + vc0 * 8);
    }
    __syncthreads();

    f32x16 sacc;
#pragma unroll
    for (int r = 0; r < 16; r++) sacc[r] = 0.f;
#pragma unroll
    for (int kc = 0; kc < 8; kc++) {
      bf16x8 kf = *(const bf16x8*)(Ks[p] + l31 * 136 + kc * 16 + half * 8);
      sacc = __builtin_amdgcn_mfma_f32_32x32x16_bf16(qf[kc], kf, sacc, 0, 0, 0);
    }

#pragma unroll
    for (int r = 0; r < 16; r++) {
      float e = exp2f(sacc[r] * SC);
      lsum[r] += e;
      int ridx = (r & 3) + 8 * (r >> 2) + 4 * half;
      Pw[ridx * 40 + l31] = f32_to_bf16(e);
    }

    bf16x8 pf[2];
#pragma unroll
    for (int kc = 0; kc < 2; kc++)
      pf[kc] = *(const bf16x8*)(Pw + l31 * 40 + kc * 16 + half * 8);
#pragma unroll
    for (int nt = 0; nt < 4; nt++)
#pragma unroll
      for (int kc = 0; kc < 2; kc++) {
        bf16x8 vf = *(const bf16x8*)(Vs[p] + (nt * 32 + l31) * 40 + kc * 16 + half * 8);
        oacc[nt] = __builtin_amdgcn_mfma_f32_32x32x16_bf16(pf[kc], vf, oacc[nt], 0, 0, 0);
      }

    const int pn = p ^ 1;
#pragma unroll
    for (int it = 0; it < 2; it++) {
      *(u16x8*)(Ks[pn] + (kkr + it * 16) * 136 + kc0 * 8) = kv[it];
      *(u16x8*)(Vs[pn] + (vd + it * 64) * 40 + vc0 * 8) = vv[it];
    }
    p = pn;
  }

#pragma unroll
  for (int r = 0; r < 16; r++) {
    float s = lsum[r];
    s += __shfl_xor(s, 1);
    s += __shfl_xor(s, 2);
    s += __shfl_xor(s, 4);
    s += __shfl_xor(s, 8);
    s += __shfl_xor(s, 16);
    lsum[r] = 1.0f / s;
  }

#pragma unroll
  for (int nt = 0; nt < 4; nt++)
#pragma unroll
    for (int r = 0; r < 16; r++) {
      int ridx = (r & 3) + 8 * (r >> 2) + 4 * half;
      int row = b * 2048 + qt * 128 + w * 32 + ridx;
      int col = h * 128 + nt * 32 + l31;
      O[(size_t)row * 2048 + col] = f32_to_bf16(oacc[nt][r] * lsum[r]);
    }
}

// ---------------- launch ----------------
extern "C" void kernel_launch(void* const* d_in, const int* in_sizes, int n_in,
                              void* d_out, int out_size, void* d_ws, size_t ws_size,
                              hipStream_t stream) {
  (void)in_sizes; (void)n_in; (void)out_size; (void)ws_size;
  const float* x     = (const float*)d_in[0];
  const float* q_w   = (const float*)d_in[1];
  const float* q_b   = (const float*)d_in[2];
  const float* kvd_w = (const float*)d_in[3];
  const float* kvd_b = (const float*)d_in[4];
  const float* kvu_w = (const float*)d_in[5];
  const float* kvu_b = (const float*)d_in[6];
  const float* out_w = (const float*)d_in[7];
  const float* out_b = (const float*)d_in[8];
  float* out = (float*)d_out;

  char* p = (char*)d_ws;
  u16* X    = (u16*)(p + 0);
  u16* W1   = (u16*)(p + (size_t)16 * 1024 * 1024);
  u16* W2   = (u16*)(p + (size_t)24 * 1024 * 1024);
  u16* Qb   = (u16*)(p + (size_t)26 * 1024 * 1024);
  u16* Lat  = (u16*)(p + (size_t)42 * 1024 * 1024);
  u16* Khat = (u16*)(p + (size_t)46 * 1024 * 1024);
  u16* Vt   = (u16*)(p + (size_t)62 * 1024 * 1024);
  u16* AO   = (u16*)(p + (size_t)78 * 1024 * 1024);

  cvt_bf16<<<dim3(8192), dim3(256), 0, stream>>>(x, X, 8388608);
  cvt_bf16<<<dim3(4096), dim3(256), 0, stream>>>(q_w, W1, 4194304);
  cvt_bf16<<<dim3(1024), dim3(256), 0, stream>>>(kvd_w, W2, 1048576);

  gemm_qlat<<<dim3(20, 32), dim3(256), 0, stream>>>(X, W1, W2, q_b, kvd_b, Qb, Lat);

  cvt_bf16<<<dim3(2048), dim3(256), 0, stream>>>(kvu_w, W1, 2097152);
  gemm_kv<<<dim3(32, 32), dim3(256), 0, stream>>>(Lat, W1, kvu_b, Khat, Vt, 512);

  cvt_bf16<<<dim3(4096), dim3(256), 0, stream>>>(out_w, X, 4194304);
  attn_kernel<<<dim3(512), dim3(256), 0, stream>>>(Qb, Khat, Vt, AO);
  gemm_f32out<<<dim3(16, 32), dim3(256), 0, stream>>>(AO, X, out_b, out, 2048, 2048);
}

// Round 8
// 386.741 us; speedup vs baseline: 1.1345x; 1.1345x over previous
//
#include <hip/hip_runtime.h>

typedef unsigned short u16;
typedef __attribute__((ext_vector_type(8))) __bf16 bf16x8;
typedef __attribute__((ext_vector_type(8))) unsigned short u16x8;
typedef __attribute__((ext_vector_type(4))) float f32x4;
typedef __attribute__((ext_vector_type(16))) float f32x16;

#define BK 32
#define TILE_ELEMS (128 * BK)
// softmax scale folded into q-projection: 1/sqrt(128) * log2(e)
#define QSCALE 0.12753706518066536f

__device__ __forceinline__ u16 f32_to_bf16(float f) {
  unsigned int u = __builtin_bit_cast(unsigned int, f);
  u += 0x7fffu + ((u >> 16) & 1u);
  return (u16)(u >> 16);
}

__device__ __forceinline__ unsigned int pack_bf16(float a, float b) {
  return (unsigned int)f32_to_bf16(a) | ((unsigned int)f32_to_bf16(b) << 16);
}

// ---------------- fused fp32 -> bf16 conversion (all 5 tensors) -------------
__global__ __launch_bounds__(256) void cvt_all(
    const float* __restrict__ x, const float* __restrict__ qw,
    const float* __restrict__ kvdw, const float* __restrict__ kvuw,
    const float* __restrict__ outw, u16* __restrict__ X, u16* __restrict__ W1,
    u16* __restrict__ W2, u16* __restrict__ W3, u16* __restrict__ W4) {
  int blk = blockIdx.x;
  const float* src;
  u16* dst;
  int base;
  if (blk < 8192)       { src = x;    dst = X;  base = blk; }
  else if (blk < 12288) { src = qw;   dst = W1; base = blk - 8192; }
  else if (blk < 13312) { src = kvdw; dst = W2; base = blk - 12288; }
  else if (blk < 15360) { src = kvuw; dst = W3; base = blk - 13312; }
  else                  { src = outw; dst = W4; base = blk - 15360; }
  int i = base * 1024 + threadIdx.x * 4;
  float4 v = *(const float4*)(src + i);
  ushort4 o;
  o.x = f32_to_bf16(v.x);
  o.y = f32_to_bf16(v.y);
  o.z = f32_to_bf16(v.z);
  o.w = f32_to_bf16(v.w);
  *(ushort4*)(dst + i) = o;
}

// ------------- GEMM core: C(128x128) = A_tile(128xK) * B_tile(128xK)^T ------
// Register-staging single-barrier double buffer (round-5 known-good).
__device__ __forceinline__ void gemm_core(const u16* __restrict__ A_tile,
                                          const u16* __restrict__ B_tile, int K,
                                          u16* As, u16* Bs, f32x4 acc[4][4]) {
  const int tid = threadIdx.x;
  const int w = tid >> 6, lane = tid & 63;
  const int wm = (w >> 1) << 6, wn = (w & 1) << 6;
  const int quad = lane >> 4, l15 = lane & 15;

  const u16* Ap = A_tile + (tid >> 2) * K + (tid & 3) * 8;
  const u16* Bp = B_tile + (tid >> 2) * K + (tid & 3) * 8;

  u16x8 ra0 = *(const u16x8*)Ap;
  u16x8 ra1 = *(const u16x8*)(Ap + 64 * K);
  u16x8 rb0 = *(const u16x8*)Bp;
  u16x8 rb1 = *(const u16x8*)(Bp + 64 * K);
  *(u16x8*)(As + tid * 8) = ra0;
  *(u16x8*)(As + (256 + tid) * 8) = ra1;
  *(u16x8*)(Bs + tid * 8) = rb0;
  *(u16x8*)(Bs + (256 + tid) * 8) = rb1;

  int p = 0;
  for (int k0 = 0; k0 < K; k0 += BK) {
    const int kn = (k0 + BK < K) ? (k0 + BK) : 0;
    ra0 = *(const u16x8*)(Ap + kn);
    ra1 = *(const u16x8*)(Ap + 64 * K + kn);
    rb0 = *(const u16x8*)(Bp + kn);
    rb1 = *(const u16x8*)(Bp + 64 * K + kn);
    __syncthreads();
    const u16* Asr = As + p * TILE_ELEMS;
    const u16* Bsr = Bs + p * TILE_ELEMS;
    bf16x8 af[4], bf[4];
#pragma unroll
    for (int i = 0; i < 4; i++)
      af[i] = *(const bf16x8*)(Asr + (wm + i * 16 + l15) * BK + quad * 8);
#pragma unroll
    for (int j = 0; j < 4; j++)
      bf[j] = *(const bf16x8*)(Bsr + (wn + j * 16 + l15) * BK + quad * 8);
#pragma unroll
    for (int i = 0; i < 4; i++)
#pragma unroll
      for (int j = 0; j < 4; j++)
        acc[i][j] =
            __builtin_amdgcn_mfma_f32_16x16x32_bf16(af[i], bf[j], acc[i][j], 0, 0, 0);
    const int pn = p ^ 1;
    u16* Asw = As + pn * TILE_ELEMS;
    u16* Bsw = Bs + pn * TILE_ELEMS;
    *(u16x8*)(Asw + tid * 8) = ra0;
    *(u16x8*)(Asw + (256 + tid) * 8) = ra1;
    *(u16x8*)(Bsw + tid * 8) = rb0;
    *(u16x8*)(Bsw + (256 + tid) * 8) = rb1;
    p = pn;
  }
}

// ---------------- fused q-proj + latent-proj (q pre-scaled by QSCALE) -------
__global__ __launch_bounds__(256) void gemm_qlat(const u16* __restrict__ X,
                                                 const u16* __restrict__ QW,
                                                 const u16* __restrict__ KVDW,
                                                 const float* __restrict__ q_b,
                                                 const float* __restrict__ kvd_b,
                                                 u16* __restrict__ Qb,
                                                 u16* __restrict__ Lat) {
  __shared__ __align__(16) u16 As[2 * TILE_ELEMS];
  __shared__ __align__(16) u16 Bs[2 * TILE_ELEMS];
  const int bn = blockIdx.x, bm = blockIdx.y;
  const bool isq = bn < 16;
  const u16* B_tile = isq ? QW + (size_t)bn * 128 * 2048
                          : KVDW + (size_t)(bn - 16) * 128 * 2048;
  f32x4 acc[4][4];
  const f32x4 z = {0.f, 0.f, 0.f, 0.f};
#pragma unroll
  for (int i = 0; i < 4; i++)
#pragma unroll
    for (int j = 0; j < 4; j++) acc[i][j] = z;
  gemm_core(X + (size_t)bm * 128 * 2048, B_tile, 2048, As, Bs, acc);

  const float* bias = isq ? q_b : kvd_b;
  u16* C = isq ? Qb : Lat;
  const int N = isq ? 2048 : 512;
  const float scale = isq ? QSCALE : 1.0f;
  const int colbase = (isq ? bn : bn - 16) * 128;

  const int tid = threadIdx.x;
  const int w = tid >> 6, lane = tid & 63;
  const int wm = (w >> 1) << 6, wn = (w & 1) << 6;
  const int quad = lane >> 4, l15 = lane & 15;
  const int row0 = bm * 128 + wm + quad * 4;
  const int col0 = colbase + wn + l15;
#pragma unroll
  for (int i = 0; i < 4; i++)
#pragma unroll
    for (int j = 0; j < 4; j++) {
      int col = col0 + j * 16;
      float bv = bias[col];
#pragma unroll
      for (int r = 0; r < 4; r++) {
        int row = row0 + i * 16 + r;
        C[(size_t)row * N + col] = f32_to_bf16((acc[i][j][r] + bv) * scale);
      }
    }
}

// ---------------- GEMM with fp32 output (final projection) ----------------
__global__ __launch_bounds__(256) void gemm_f32out(const u16* __restrict__ A,
                                                   const u16* __restrict__ B,
                                                   const float* __restrict__ bias,
                                                   float* __restrict__ C, int K, int N) {
  __shared__ __align__(16) u16 As[2 * TILE_ELEMS];
  __shared__ __align__(16) u16 Bs[2 * TILE_ELEMS];
  f32x4 acc[4][4];
  const f32x4 z = {0.f, 0.f, 0.f, 0.f};
#pragma unroll
  for (int i = 0; i < 4; i++)
#pragma unroll
    for (int j = 0; j < 4; j++) acc[i][j] = z;
  gemm_core(A + (size_t)blockIdx.y * 128 * K, B + (size_t)blockIdx.x * 128 * K, K,
            As, Bs, acc);

  const int tid = threadIdx.x;
  const int w = tid >> 6, lane = tid & 63;
  const int wm = (w >> 1) << 6, wn = (w & 1) << 6;
  const int quad = lane >> 4, l15 = lane & 15;
  const int row0 = blockIdx.y * 128 + wm + quad * 4;
  const int col0 = blockIdx.x * 128 + wn + l15;
#pragma unroll
  for (int i = 0; i < 4; i++)
#pragma unroll
    for (int j = 0; j < 4; j++) {
      int col = col0 + j * 16;
      float bv = bias[col];
#pragma unroll
      for (int r = 0; r < 4; r++) {
        int row = row0 + i * 16 + r;
        C[(size_t)row * N + col] = acc[i][j][r] + bv;
      }
    }
}

// ------------- GEMM3: kv-up with scatter epilogue: K->(b,h,s,d), V->(b,h,d,s) -
__global__ __launch_bounds__(256) void gemm_kv(const u16* __restrict__ A,
                                               const u16* __restrict__ B,
                                               const float* __restrict__ bias,
                                               u16* __restrict__ Khat,
                                               u16* __restrict__ Vt, int K) {
  __shared__ __align__(16) u16 As[2 * TILE_ELEMS];
  __shared__ __align__(16) u16 Bs[2 * TILE_ELEMS];
  f32x4 acc[4][4];
  const f32x4 z = {0.f, 0.f, 0.f, 0.f};
#pragma unroll
  for (int i = 0; i < 4; i++)
#pragma unroll
    for (int j = 0; j < 4; j++) acc[i][j] = z;
  gemm_core(A + (size_t)blockIdx.y * 128 * K, B + (size_t)blockIdx.x * 128 * K, K,
            As, Bs, acc);

  const int tid = threadIdx.x;
  const int w = tid >> 6, lane = tid & 63;
  const int wm = (w >> 1) << 6, wn = (w & 1) << 6;
  const int quad = lane >> 4, l15 = lane & 15;
  const int row0 = blockIdx.y * 128 + wm + quad * 4;
  const int col0 = blockIdx.x * 128 + wn + l15;
#pragma unroll
  for (int i = 0; i < 4; i++)
#pragma unroll
    for (int j = 0; j < 4; j++) {
      int n = col0 + j * 16;
      float bv = bias[n];
#pragma unroll
      for (int r = 0; r < 4; r++) {
        int row = row0 + i * 16 + r;   // row = b*2048 + s
        int bb = row >> 11, s = row & 2047;
        u16 val = f32_to_bf16(acc[i][j][r] + bv);
        if (n < 2048) {
          int h = n >> 7, d = n & 127;
          Khat[((size_t)(bb * 16 + h) * 2048 + s) * 128 + d] = val;
        } else {
          int h = (n - 2048) >> 7, d = n & 127;
          Vt[((size_t)(bb * 16 + h) * 128 + d) * 2048 + s] = val;
        }
      }
    }
}

// ---------------- attention: S^T trick — P stays in registers ----------------
// S^T = K·Q^T (mfma(kf,qf)): C lane = q-row, regs = keys. P C-regs are then a
// valid PV A-operand (lane=m=q-row; reg r = HW k-slot half*8+r = key
// (r&3)+8*(r>>2)+4*half). V is staged with that permutation baked in: within
// each 16-key group, 4-key sub-groups written at rev2(sub) -> slot order
// {0,8..11->? } i.e. sub 0,1,2,3 -> slot-groups 0,2,1,3.
__global__ __launch_bounds__(256) void attn_kernel(const u16* __restrict__ Q,
                                                   const u16* __restrict__ Khat,
                                                   const u16* __restrict__ Vt,
                                                   u16* __restrict__ O) {
  __shared__ __align__(16) u16 Ks[2][32 * 136];   // keys x dims (stride 136)
  __shared__ __align__(16) u16 Vs[2][128 * 40];   // dims x keys-permuted (stride 40)

  const int tid = threadIdx.x;
  const int w = tid >> 6, lane = tid & 63;
  const int l31 = lane & 31, half = lane >> 5;
  const int qt = blockIdx.x & 15;
  const int h = (blockIdx.x >> 4) & 15;
  const int b = blockIdx.x >> 8;
  const int bh = b * 16 + h;

  // Q fragments (B-operand now; same layout): n=lane&31=q-row, k=half*8+j
  bf16x8 qf[8];
  {
    const u16* qrow = Q + (size_t)(b * 2048 + qt * 128 + w * 32 + l31) * 2048 +
                      h * 128 + half * 8;
#pragma unroll
    for (int kc = 0; kc < 8; kc++) qf[kc] = *(const bf16x8*)(qrow + kc * 16);
  }

  f32x16 oacc[4];
#pragma unroll
  for (int nt = 0; nt < 4; nt++)
#pragma unroll
    for (int r = 0; r < 16; r++) oacc[nt][r] = 0.f;
  float lsum = 0.f;  // per-lane: this lane's q-row, half of the keys

  const u16* Kg = Khat + (size_t)bh * 2048 * 128;
  const u16* Vg = Vt + (size_t)bh * 128 * 2048;

  const int kkr = tid >> 4, kc0 = tid & 15;
  const int vd = tid >> 2, vc0 = tid & 3;
  // permuted V write offsets (elements): sub-groups 0,1,2,3 -> 0,2,1,3
  const int vlo = (vc0 >> 1) * 16 + (vc0 & 1) * 4;  // {0,4,16,20}
  const int vhi = vlo + 8;

  u16x8 kv[2], vv[2];
#pragma unroll
  for (int it = 0; it < 2; it++) {
    kv[it] = *(const u16x8*)(Kg + (size_t)(kkr + it * 16) * 128 + kc0 * 8);
    vv[it] = *(const u16x8*)(Vg + (size_t)(vd + it * 64) * 2048 + vc0 * 8);
  }
#pragma unroll
  for (int it = 0; it < 2; it++) {
    *(u16x8*)(Ks[0] + (kkr + it * 16) * 136 + kc0 * 8) = kv[it];
    const unsigned long long* vp = (const unsigned long long*)&vv[it];
    *(unsigned long long*)(Vs[0] + (vd + it * 64) * 40 + vlo) = vp[0];
    *(unsigned long long*)(Vs[0] + (vd + it * 64) * 40 + vhi) = vp[1];
  }

  int p = 0;
  for (int key0 = 0; key0 < 2048; key0 += 32) {
    const int kn = (key0 + 32 < 2048) ? (key0 + 32) : 0;
#pragma unroll
    for (int it = 0; it < 2; it++) {
      kv[it] = *(const u16x8*)(Kg + (size_t)(kn + kkr + it * 16) * 128 + kc0 * 8);
      vv[it] = *(const u16x8*)(Vg + (size_t)(vd + it * 64) * 2048 + kn + vc0 * 8);
    }
    __syncthreads();

    // S^T = K Q^T : 32 keys x 32 q-rows (A = K-frag, B = Q-frag)
    f32x16 sacc;
#pragma unroll
    for (int r = 0; r < 16; r++) sacc[r] = 0.f;
#pragma unroll
    for (int kc = 0; kc < 8; kc++) {
      bf16x8 kf = *(const bf16x8*)(Ks[p] + l31 * 136 + kc * 16 + half * 8);
      sacc = __builtin_amdgcn_mfma_f32_32x32x16_bf16(kf, qf[kc], sacc, 0, 0, 0);
    }

    // P = exp2(S^T) in registers (scale pre-folded into Q); pack to A-frags
    float e[16];
#pragma unroll
    for (int r = 0; r < 16; r++) {
      e[r] = exp2f(sacc[r]);
      lsum += e[r];
    }
    union { unsigned int u[4]; bf16x8 v; } p0, p1;
#pragma unroll
    for (int i = 0; i < 4; i++) {
      p0.u[i] = pack_bf16(e[2 * i], e[2 * i + 1]);
      p1.u[i] = pack_bf16(e[8 + 2 * i], e[9 + 2 * i]);
    }

    // O += P V (A = P regs, B = permuted Vs)
#pragma unroll
    for (int nt = 0; nt < 4; nt++) {
      bf16x8 vf0 = *(const bf16x8*)(Vs[p] + (nt * 32 + l31) * 40 + half * 8);
      bf16x8 vf1 = *(const bf16x8*)(Vs[p] + (nt * 32 + l31) * 40 + 16 + half * 8);
      oacc[nt] = __builtin_amdgcn_mfma_f32_32x32x16_bf16(p0.v, vf0, oacc[nt], 0, 0, 0);
      oacc[nt] = __builtin_amdgcn_mfma_f32_32x32x16_bf16(p1.v, vf1, oacc[nt], 0, 0, 0);
    }

    // stage next tile into the other buffer
    const int pn = p ^ 1;
#pragma unroll
    for (int it = 0; it < 2; it++) {
      *(u16x8*)(Ks[pn] + (kkr + it * 16) * 136 + kc0 * 8) = kv[it];
      const unsigned long long* vp = (const unsigned long long*)&vv[it];
      *(unsigned long long*)(Vs[pn] + (vd + it * 64) * 40 + vlo) = vp[0];
      *(unsigned long long*)(Vs[pn] + (vd + it * 64) * 40 + vhi) = vp[1];
    }
    p = pn;
  }

  // lsum: lanes l and l+32 hold complementary key-halves of q-row l31
  lsum += __shfl_xor(lsum, 32);
  float inv = 1.0f / lsum;
  float wr[16];
#pragma unroll
  for (int r = 0; r < 16; r++) {
    int ridx = (r & 3) + 8 * (r >> 2) + 4 * half;
    wr[r] = __shfl(inv, ridx);  // lane ridx holds inv for q-row ridx
  }

#pragma unroll
  for (int nt = 0; nt < 4; nt++)
#pragma unroll
    for (int r = 0; r < 16; r++) {
      int ridx = (r & 3) + 8 * (r >> 2) + 4 * half;
      int row = b * 2048 + qt * 128 + w * 32 + ridx;
      int col = h * 128 + nt * 32 + l31;
      O[(size_t)row * 2048 + col] = f32_to_bf16(oacc[nt][r] * wr[r]);
    }
}

// ---------------- launch ----------------
extern "C" void kernel_launch(void* const* d_in, const int* in_sizes, int n_in,
                              void* d_out, int out_size, void* d_ws, size_t ws_size,
                              hipStream_t stream) {
  (void)in_sizes; (void)n_in; (void)out_size; (void)ws_size;
  const float* x     = (const float*)d_in[0];
  const float* q_w   = (const float*)d_in[1];
  const float* q_b   = (const float*)d_in[2];
  const float* kvd_w = (const float*)d_in[3];
  const float* kvd_b = (const float*)d_in[4];
  const float* kvu_w = (const float*)d_in[5];
  const float* kvu_b = (const float*)d_in[6];
  const float* out_w = (const float*)d_in[7];
  const float* out_b = (const float*)d_in[8];
  float* out = (float*)d_out;

  // Workspace (106 MB): X 16 | W1 8 | W2 2 | W3 4 | W4 8 | Qb 16 | Lat 4 |
  // Khat 16 | Vt 16 | AO 16
  char* p = (char*)d_ws;
  u16* X    = (u16*)(p + 0);
  u16* W1   = (u16*)(p + (size_t)16 * 1024 * 1024);
  u16* W2   = (u16*)(p + (size_t)24 * 1024 * 1024);
  u16* W3   = (u16*)(p + (size_t)26 * 1024 * 1024);
  u16* W4   = (u16*)(p + (size_t)30 * 1024 * 1024);
  u16* Qb   = (u16*)(p + (size_t)38 * 1024 * 1024);
  u16* Lat  = (u16*)(p + (size_t)54 * 1024 * 1024);
  u16* Khat = (u16*)(p + (size_t)58 * 1024 * 1024);
  u16* Vt   = (u16*)(p + (size_t)74 * 1024 * 1024);
  u16* AO   = (u16*)(p + (size_t)90 * 1024 * 1024);

  cvt_all<<<dim3(19456), dim3(256), 0, stream>>>(x, q_w, kvd_w, kvu_w, out_w,
                                                 X, W1, W2, W3, W4);
  gemm_qlat<<<dim3(20, 32), dim3(256), 0, stream>>>(X, W1, W2, q_b, kvd_b, Qb, Lat);
  gemm_kv<<<dim3(32, 32), dim3(256), 0, stream>>>(Lat, W3, kvu_b, Khat, Vt, 512);
  attn_kernel<<<dim3(512), dim3(256), 0, stream>>>(Qb, Khat, Vt, AO);
  gemm_f32out<<<dim3(16, 32), dim3(256), 0, stream>>>(AO, W4, out_b, out, 2048, 2048);
}